// Round 4
// baseline (884.859 us; speedup 1.0000x reference)
//
#include <hip/hip_runtime.h>
#include <stdint.h>

#define KSTEPS 20
#define EPB 4          // batch elements per block
#define NBLOCKS 1024   // 4096 / EPB
#define NTHREADS 512

// ---- LDS layout (bytes) ----
// wq    : uint32 [4][128][64]   (bf16-pairs, pair-rotated swizzle) = 131072
// hcatT : float  [128][4] grad half (+h1T full 256 rows)           =   4096  @131072
// h0T   : float  [256][4]                                          =   4096  @135168
// xbuf  : float  [4][128]                                          =   2048  @139264
// xnext : float4 [128]     (x part of next hcat, separate buffer)  =   2048  @141312
// total = 143360
#define SMEM_BYTES 143360

typedef float v2f __attribute__((ext_vector_type(2)));

static __device__ __forceinline__ float bflo(uint32_t u) {
    union { uint32_t u; float f; } v; v.u = u << 16; return v.f;
}
static __device__ __forceinline__ float bfhi(uint32_t u) {
    union { uint32_t u; float f; } v; v.u = u & 0xffff0000u; return v.f;
}
static __device__ __forceinline__ uint32_t f2bf(float x) {  // RNE round to bf16 (as u16)
    union { float f; uint32_t u; } v; v.f = x;
    return (v.u + 0x7fffu + ((v.u >> 16) & 1u)) >> 16;
}
static __device__ __forceinline__ uint32_t packbf2(float a, float b) {
    return f2bf(a) | (f2bf(b) << 16);
}
static __device__ __forceinline__ uint32_t u4get(const uint4& v, int i) {
    switch (i) { case 0: return v.x; case 1: return v.y; case 2: return v.z; default: return v.w; }
}
static __device__ __forceinline__ v2f fma2(v2f a, v2f b, v2f c) {
    return __builtin_elementwise_fma(a, b, c);   // -> v_pk_fma_f32 on gfx950
}
static __device__ __forceinline__ v2f shflx2(v2f v, int m) {
    v2f r; r.x = __shfl_xor(v.x, m); r.y = __shfl_xor(v.y, m); return r;
}

// Pack shared MLP weights fp32 -> bf16 in layout [c][r][m] : Wp[(c*R + r)*8 + m] = W[r][8c+m]
// W0: R=256 (65536 elems), W1: R=256 (65536), V: R=128 (32768). Total 163840 bf16 = 320 KB.
__global__ void prep_kernel(const float* __restrict__ W0, const float* __restrict__ W1,
                            const float* __restrict__ V, uint16_t* __restrict__ out)
{
    int i = blockIdx.x * 256 + threadIdx.x;   // 640 blocks * 256 = 163840
    float v;
    if (i < 65536) {
        int c = i >> 11, rest = i & 2047, r = rest >> 3, m = rest & 7;
        v = W0[r * 256 + c * 8 + m];
    } else if (i < 131072) {
        int j = i - 65536;
        int c = j >> 11, rest = j & 2047, r = rest >> 3, m = rest & 7;
        v = W1[r * 256 + c * 8 + m];
    } else {
        int j = i - 131072;
        int c = j >> 10, rest = j & 1023, r = rest >> 3, m = rest & 7;
        v = V[r * 256 + c * 8 + m];
    }
    out[i] = (uint16_t)f2bf(v);
}

// Round-3 state: spill-free (WRITE 31MB), wp L2-resident (FETCH 145MB), 744us,
// VALUBusy ~60%. Now VALU-issue + barrier bound. This round:
//  (a) v2f accumulators + elementwise_fma -> v_pk_fma_f32 (2 MACs/instr; the
//      batch dim is already pair-contiguous in the float4 activation reads).
//  (b) MLP K-quarter partials remapped into the SAME wave (lane = kq*16+rr):
//      butterfly __shfl_xor(16/32) replaces the part4 LDS round-trip + barrier +
//      serial jq==0 tail. Barriers/step 8 -> 4. xnext buffer breaks the V-phase
//      WAR hazard that forced the old extra barrier.
__global__
__attribute__((amdgpu_flat_work_group_size(512, 512), amdgpu_waves_per_eu(2, 2)))
void mlprnn_main(
    const float* __restrict__ w, const float* __restrict__ b,
    const uint16_t* __restrict__ wp, float* __restrict__ out)
{
    extern __shared__ char smem[];
    uint32_t* wq    = (uint32_t*)smem;
    float*    hcatT = (float*)(smem + 131072);
    float*    h0T   = (float*)(smem + 135168);
    float*    xbuf  = (float*)(smem + 139264);
    float4*   hcatT4  = (float4*)hcatT;
    float4*   h0T4    = (float4*)h0T;
    float4*   xnextT4 = (float4*)(smem + 141312);

    const int t  = threadIdx.x;
    const int e0 = blockIdx.x * EPB;

    // ---- load this block's 4 w matrices -> LDS bf16, pair-rotated swizzle ----
    {
        const float4* wg = (const float4*)w;
        for (int it = 0; it < 32; ++it) {
            int g  = it * NTHREADS + t;       // 0..16383
            int e  = g >> 12;
            int gg = g & 4095;
            int r  = gg >> 5, q = gg & 31;
            float4 f = wg[(size_t)(e0 + e) * 4096 + gg];
            int s = (q + r) & 31;
            uint32_t* dst = wq + ((e * 128 + r) * 64 + 2 * s);
            dst[0] = packbf2(f.x, f.y);
            dst[1] = packbf2(f.z, f.w);
        }
    }
    // init x = 0 (xbuf) and x-part of hcat (xnext) = 0
    xbuf[t] = 0.f;
    if (t < 128) xnextT4[t] = make_float4(0.f, 0.f, 0.f, 0.f);
    __syncthreads();

    // ---- matvec role: 2 waves per element, lane-per-row (unchanged) ----
    const int e_mv = t >> 7;                         // element 0..3
    const int r_mv = ((t >> 6) & 1) * 64 + (t & 63); // row 0..127
    const float breg = b[(size_t)(e0 + e_mv) * 128 + r_mv];
    const uint32_t* wrow = wq + ((e_mv * 128 + r_mv) * 64);
    const float4*   xv   = (const float4*)(xbuf + e_mv * 128);
    const int hcat_wr = r_mv * 4 + e_mv;

    // ---- MLP role: wave-local K-quarters ----
    // lane l = kq*16 + rr ; rows (r0, r0+128), cols [kq*64, kq*64+64)
    const int l  = t & 63, wvi = t >> 6;
    const int rr = l & 15, kq = l >> 4;
    const int r0 = wvi * 16 + rr;                    // 0..127

    const uint4* w0p = (const uint4*)wp;       // [32][256] uint4 (8 bf16 each)
    const uint4* w1p = w0p + 32 * 256;
    const uint4* vp  = w1p + 32 * 256;         // [32][128]

    // h0 phase source: cols 0..127 = grad (hcatT4), cols 128..255 = x (xnextT4)
    const float4* h0src = (kq < 2) ? hcatT4 : (xnextT4 - 128);

    for (int k = 0; k < KSTEPS; ++k) {
        // ================= grad = w @ x - b ;  hcatT[r] = -grad =================
        {
            float acc = 0.f;
            #pragma unroll 8
            for (int j4 = 0; j4 < 32; ++j4) {
                int s = (j4 + r_mv) & 31;
                uint2 u = *(const uint2*)(wrow + 2 * s);
                float4 xq = xv[j4];
                acc += bflo(u.x) * xq.x + bfhi(u.x) * xq.y
                     + bflo(u.y) * xq.z + bfhi(u.y) * xq.w;
            }
            hcatT[hcat_wr] = breg - acc;   // -grad
        }
        __syncthreads();   // B1

        // ================= h0 = relu(W0 @ hcat) -> h0T =================
        {
            v2f a0l = {0.f, 0.f}, a0h = {0.f, 0.f};
            v2f a1l = {0.f, 0.f}, a1h = {0.f, 0.f};
            #pragma unroll 4
            for (int ci = 0; ci < 8; ++ci) {
                int c8 = kq * 8 + ci;
                uint4 u0 = w0p[c8 * 256 + r0];
                uint4 u1 = w0p[c8 * 256 + r0 + 128];
                #pragma unroll
                for (int m = 0; m < 8; ++m) {
                    float4 h = h0src[c8 * 8 + m];
                    uint32_t q0 = u4get(u0, m >> 1), q1 = u4get(u1, m >> 1);
                    float f0 = (m & 1) ? bfhi(q0) : bflo(q0);
                    float f1 = (m & 1) ? bfhi(q1) : bflo(q1);
                    v2f s0 = {f0, f0}, s1 = {f1, f1};
                    v2f hl = {h.x, h.y}, hh = {h.z, h.w};
                    a0l = fma2(s0, hl, a0l); a0h = fma2(s0, hh, a0h);
                    a1l = fma2(s1, hl, a1l); a1h = fma2(s1, hh, a1h);
                }
            }
            // reduce across kq (lanes ^16, ^32)
            a0l += shflx2(a0l, 16); a0h += shflx2(a0h, 16);
            a1l += shflx2(a1l, 16); a1h += shflx2(a1h, 16);
            a0l += shflx2(a0l, 32); a0h += shflx2(a0h, 32);
            a1l += shflx2(a1l, 32); a1h += shflx2(a1h, 32);
            if (kq == 0) {
                float4 o0 = make_float4(fmaxf(a0l.x, 0.f), fmaxf(a0l.y, 0.f),
                                        fmaxf(a0h.x, 0.f), fmaxf(a0h.y, 0.f));
                float4 o1 = make_float4(fmaxf(a1l.x, 0.f), fmaxf(a1l.y, 0.f),
                                        fmaxf(a1h.x, 0.f), fmaxf(a1h.y, 0.f));
                h0T4[r0]       = o0;
                h0T4[r0 + 128] = o1;
            }
            __syncthreads();   // B2
        }

        // ================= h1 = relu(W1 @ h0) -> hcatT (reused as h1T) =================
        {
            v2f a0l = {0.f, 0.f}, a0h = {0.f, 0.f};
            v2f a1l = {0.f, 0.f}, a1h = {0.f, 0.f};
            #pragma unroll 4
            for (int ci = 0; ci < 8; ++ci) {
                int c8 = kq * 8 + ci;
                uint4 u0 = w1p[c8 * 256 + r0];
                uint4 u1 = w1p[c8 * 256 + r0 + 128];
                #pragma unroll
                for (int m = 0; m < 8; ++m) {
                    float4 h = h0T4[c8 * 8 + m];
                    uint32_t q0 = u4get(u0, m >> 1), q1 = u4get(u1, m >> 1);
                    float f0 = (m & 1) ? bfhi(q0) : bflo(q0);
                    float f1 = (m & 1) ? bfhi(q1) : bflo(q1);
                    v2f s0 = {f0, f0}, s1 = {f1, f1};
                    v2f hl = {h.x, h.y}, hh = {h.z, h.w};
                    a0l = fma2(s0, hl, a0l); a0h = fma2(s0, hh, a0h);
                    a1l = fma2(s1, hl, a1l); a1h = fma2(s1, hh, a1h);
                }
            }
            a0l += shflx2(a0l, 16); a0h += shflx2(a0h, 16);
            a1l += shflx2(a1l, 16); a1h += shflx2(a1h, 16);
            a0l += shflx2(a0l, 32); a0h += shflx2(a0h, 32);
            a1l += shflx2(a1l, 32); a1h += shflx2(a1h, 32);
            if (kq == 0) {
                float4 o0 = make_float4(fmaxf(a0l.x, 0.f), fmaxf(a0l.y, 0.f),
                                        fmaxf(a0h.x, 0.f), fmaxf(a0h.y, 0.f));
                float4 o1 = make_float4(fmaxf(a1l.x, 0.f), fmaxf(a1l.y, 0.f),
                                        fmaxf(a1h.x, 0.f), fmaxf(a1h.y, 0.f));
                hcatT4[r0]       = o0;   // h1T rows 0..127
                hcatT4[r0 + 128] = o1;   // h1T rows 128..255
            }
            __syncthreads();   // B3
        }

        // ================= x_new = V @ h1 ; update xbuf, xnext, (final) out =================
        {
            v2f al = {0.f, 0.f}, ah = {0.f, 0.f};
            #pragma unroll 4
            for (int ci = 0; ci < 8; ++ci) {
                int c8 = kq * 8 + ci;
                uint4 u = vp[c8 * 128 + r0];
                #pragma unroll
                for (int m = 0; m < 8; ++m) {
                    float4 h = hcatT4[c8 * 8 + m];   // h1T
                    uint32_t q = u4get(u, m >> 1);
                    float f = (m & 1) ? bfhi(q) : bflo(q);
                    v2f s = {f, f};
                    v2f hl = {h.x, h.y}, hh = {h.z, h.w};
                    al = fma2(s, hl, al); ah = fma2(s, hh, ah);
                }
            }
            al += shflx2(al, 16); ah += shflx2(ah, 16);
            al += shflx2(al, 32); ah += shflx2(ah, 32);
            if (kq == 0) {
                float4 a = make_float4(al.x, al.y, ah.x, ah.y);
                xbuf[0 * 128 + r0] = a.x;
                xbuf[1 * 128 + r0] = a.y;
                xbuf[2 * 128 + r0] = a.z;
                xbuf[3 * 128 + r0] = a.w;
                xnextT4[r0] = a;           // x part of next hcat
                if (k == KSTEPS - 1) {
                    out[(size_t)(e0 + 0) * 128 + r0] = a.x;
                    out[(size_t)(e0 + 1) * 128 + r0] = a.y;
                    out[(size_t)(e0 + 2) * 128 + r0] = a.z;
                    out[(size_t)(e0 + 3) * 128 + r0] = a.w;
                }
            }
            __syncthreads();   // B4
        }
    }
}

extern "C" void kernel_launch(void* const* d_in, const int* in_sizes, int n_in,
                              void* d_out, int out_size, void* d_ws, size_t ws_size,
                              hipStream_t stream)
{
    const float* w  = (const float*)d_in[0];   // [4096,128,128]
    const float* b  = (const float*)d_in[1];   // [4096,128]
    const float* W0 = (const float*)d_in[2];   // [256,256]
    const float* W1 = (const float*)d_in[3];   // [256,256]
    const float* V  = (const float*)d_in[4];   // [128,256]
    float* out = (float*)d_out;                // [4096,128]
    uint16_t* wp = (uint16_t*)d_ws;            // 320 KB packed bf16 weights

    prep_kernel<<<640, 256, 0, stream>>>(W0, W1, V, wp);

    hipFuncSetAttribute((const void*)mlprnn_main,
                        hipFuncAttributeMaxDynamicSharedMemorySize, SMEM_BYTES);
    mlprnn_main<<<NBLOCKS, NTHREADS, SMEM_BYTES, stream>>>(w, b, wp, out);
}

// Round 5
// 816.588 us; speedup vs baseline: 1.0836x; 1.0836x over previous
//
#include <hip/hip_runtime.h>
#include <stdint.h>

#define KSTEPS 20
#define EPB 4          // batch elements per block
#define NBLOCKS 1024   // 4096 / EPB
#define NTHREADS 512

// ---- LDS layout (bytes) ----
// Activation arrays use "bank-phase" padding: column c stored at
// byte c*16 + (c>>6)*32  (one 32B gap per 64-column quarter), so the four
// wave-local K-quarter groups (kq = lane>>4) read banks 4m + 8*kq -> disjoint.
// wq    : uint32 [4][128][64] bf16-pairs, pair-rotated swizzle  = 131072 @0
// grad  : 128 cols padded (2080)                                 @131072  (bank 0)
// h0T   : 256 cols padded (4192)                                 @133248  (bank 0)
// h1T   : 256 cols padded (4192)                                 @137472  (bank 0)
// xnext : 128 cols padded (2080)                                 @141760  (bank 16)
// xbuf  : float [4][128] = 2048                                  @143872
#define WQ_OFF    0
#define GRAD_OFF  131072
#define H0_OFF    133248
#define H1_OFF    137472
#define XNEXT_OFF 141760
#define XBUF_OFF  143872
#define SMEM_BYTES 145920

typedef float v2f __attribute__((ext_vector_type(2)));

static __device__ __forceinline__ float bflo(uint32_t u) {
    union { uint32_t u; float f; } v; v.u = u << 16; return v.f;
}
static __device__ __forceinline__ float bfhi(uint32_t u) {
    union { uint32_t u; float f; } v; v.u = u & 0xffff0000u; return v.f;
}
static __device__ __forceinline__ uint32_t f2bf(float x) {  // RNE round to bf16 (as u16)
    union { float f; uint32_t u; } v; v.f = x;
    return (v.u + 0x7fffu + ((v.u >> 16) & 1u)) >> 16;
}
static __device__ __forceinline__ uint32_t packbf2(float a, float b) {
    return f2bf(a) | (f2bf(b) << 16);
}
static __device__ __forceinline__ uint32_t u4get(const uint4& v, int i) {
    switch (i) { case 0: return v.x; case 1: return v.y; case 2: return v.z; default: return v.w; }
}
static __device__ __forceinline__ v2f fma2(v2f a, v2f b, v2f c) {
    return __builtin_elementwise_fma(a, b, c);   // -> v_pk_fma_f32 on gfx950
}
static __device__ __forceinline__ v2f shflx2(v2f v, int m) {
    v2f r; r.x = __shfl_xor(v.x, m); r.y = __shfl_xor(v.y, m); return r;
}
// padded byte offset of activation column c within its array
static __device__ __forceinline__ int wcol(int c) { return c * 16 + (c >> 6) * 32; }

// Pack shared MLP weights fp32 -> bf16 in layout [c][r][m] : Wp[(c*R + r)*8 + m] = W[r][8c+m]
// W0: R=256 (65536 elems), W1: R=256 (65536), V: R=128 (32768). Total 163840 bf16 = 320 KB.
__global__ void prep_kernel(const float* __restrict__ W0, const float* __restrict__ W1,
                            const float* __restrict__ V, uint16_t* __restrict__ out)
{
    int i = blockIdx.x * 256 + threadIdx.x;   // 640 blocks * 256 = 163840
    float v;
    if (i < 65536) {
        int c = i >> 11, rest = i & 2047, r = rest >> 3, m = rest & 7;
        v = W0[r * 256 + c * 8 + m];
    } else if (i < 131072) {
        int j = i - 65536;
        int c = j >> 11, rest = j & 2047, r = rest >> 3, m = rest & 7;
        v = W1[r * 256 + c * 8 + m];
    } else {
        int j = i - 131072;
        int c = j >> 10, rest = j & 1023, r = rest >> 3, m = rest & 7;
        v = V[r * 256 + c * 8 + m];
    }
    out[i] = (uint16_t)f2bf(v);
}

// Round-4 post-mortem: wave-local K-quarters put 4 kq values in each activation
// ds_read_b128; their addresses differ by kq*1024B == 0 mod 128B -> 4-way bank
// conflict on EVERY activation read (SQ_LDS_BANK_CONFLICT 2M -> 128M; ~4 extra
// cyc x 31M reads). pk_fma itself worked (VALUBusy 60->48% at +19% time).
// Fix: bank-phase padding (32B gap per 64-col quarter) -> banks 4m+8kq, disjoint
// across kq. 96B extra LDS, no dynamic indexing, reads become base+imm ds_read.
__global__
__attribute__((amdgpu_flat_work_group_size(512, 512), amdgpu_waves_per_eu(2, 2)))
void mlprnn_main(
    const float* __restrict__ w, const float* __restrict__ b,
    const uint16_t* __restrict__ wp, float* __restrict__ out)
{
    extern __shared__ char smem[];
    uint32_t* wq   = (uint32_t*)(smem + WQ_OFF);
    float*    xbuf = (float*)(smem + XBUF_OFF);

    const int t  = threadIdx.x;
    const int e0 = blockIdx.x * EPB;

    // ---- load this block's 4 w matrices -> LDS bf16, pair-rotated swizzle ----
    {
        const float4* wg = (const float4*)w;
        for (int it = 0; it < 32; ++it) {
            int g  = it * NTHREADS + t;       // 0..16383
            int e  = g >> 12;
            int gg = g & 4095;
            int r  = gg >> 5, q = gg & 31;
            float4 f = wg[(size_t)(e0 + e) * 4096 + gg];
            int s = (q + r) & 31;
            uint32_t* dst = wq + ((e * 128 + r) * 64 + 2 * s);
            dst[0] = packbf2(f.x, f.y);
            dst[1] = packbf2(f.z, f.w);
        }
    }
    // init x = 0 (xbuf) and x-part of hcat (xnext) = 0
    xbuf[t] = 0.f;
    if (t < 128) *(float4*)(smem + XNEXT_OFF + wcol(t)) = make_float4(0.f, 0.f, 0.f, 0.f);
    __syncthreads();

    // ---- matvec role: 2 waves per element, lane-per-row (unchanged) ----
    const int e_mv = t >> 7;                         // element 0..3
    const int r_mv = ((t >> 6) & 1) * 64 + (t & 63); // row 0..127
    const float breg = b[(size_t)(e0 + e_mv) * 128 + r_mv];
    const uint32_t* wrow = wq + ((e_mv * 128 + r_mv) * 64);
    const float4*   xv   = (const float4*)(xbuf + e_mv * 128);
    char* const grad_wr = smem + GRAD_OFF + wcol(r_mv) + e_mv * 4;

    // ---- MLP role: wave-local K-quarters ----
    // lane l = kq*16 + rr ; rows (r0, r0+128), cols [kq*64, kq*64+64)
    const int l  = t & 63, wvi = t >> 6;
    const int rr = l & 15, kq = l >> 4;
    const int r0 = wvi * 16 + rr;                    // 0..127

    const uint4* w0p = (const uint4*)wp;       // [32][256] uint4 (8 bf16 each)
    const uint4* w1p = w0p + 32 * 256;
    const uint4* vp  = w1p + 32 * 256;         // [32][128]

    // per-thread activation base pointers (bank phase 8*kq baked in)
    const char* hq_base = smem + ((kq < 2) ? (GRAD_OFF + kq * 1056)
                                           : (XNEXT_OFF + (kq - 2) * 1056));
    const char* h0_base = smem + H0_OFF + kq * 1056;
    const char* h1_base = smem + H1_OFF + kq * 1056;

    for (int k = 0; k < KSTEPS; ++k) {
        // ================= grad = w @ x - b ;  grad[r] = -(w@x - b) =================
        {
            float acc = 0.f;
            #pragma unroll 8
            for (int j4 = 0; j4 < 32; ++j4) {
                int s = (j4 + r_mv) & 31;
                uint2 u = *(const uint2*)(wrow + 2 * s);
                float4 xq = xv[j4];
                acc += bflo(u.x) * xq.x + bfhi(u.x) * xq.y
                     + bflo(u.y) * xq.z + bfhi(u.y) * xq.w;
            }
            *(float*)grad_wr = breg - acc;   // -grad
        }
        __syncthreads();   // B1

        // ================= h0 = relu(W0 @ hcat) -> h0T =================
        {
            v2f a0l = {0.f, 0.f}, a0h = {0.f, 0.f};
            v2f a1l = {0.f, 0.f}, a1h = {0.f, 0.f};
            #pragma unroll 4
            for (int ci = 0; ci < 8; ++ci) {
                int c8 = kq * 8 + ci;
                uint4 u0 = w0p[c8 * 256 + r0];
                uint4 u1 = w0p[c8 * 256 + r0 + 128];
                #pragma unroll
                for (int m = 0; m < 8; ++m) {
                    float4 h = *(const float4*)(hq_base + ci * 128 + m * 16);
                    uint32_t q0 = u4get(u0, m >> 1), q1 = u4get(u1, m >> 1);
                    float f0 = (m & 1) ? bfhi(q0) : bflo(q0);
                    float f1 = (m & 1) ? bfhi(q1) : bflo(q1);
                    v2f s0 = {f0, f0}, s1 = {f1, f1};
                    v2f hl = {h.x, h.y}, hh = {h.z, h.w};
                    a0l = fma2(s0, hl, a0l); a0h = fma2(s0, hh, a0h);
                    a1l = fma2(s1, hl, a1l); a1h = fma2(s1, hh, a1h);
                }
            }
            // reduce across kq (lanes ^16, ^32)
            a0l += shflx2(a0l, 16); a0h += shflx2(a0h, 16);
            a1l += shflx2(a1l, 16); a1h += shflx2(a1h, 16);
            a0l += shflx2(a0l, 32); a0h += shflx2(a0h, 32);
            a1l += shflx2(a1l, 32); a1h += shflx2(a1h, 32);
            if (kq == 0) {
                float4 o0 = make_float4(fmaxf(a0l.x, 0.f), fmaxf(a0l.y, 0.f),
                                        fmaxf(a0h.x, 0.f), fmaxf(a0h.y, 0.f));
                float4 o1 = make_float4(fmaxf(a1l.x, 0.f), fmaxf(a1l.y, 0.f),
                                        fmaxf(a1h.x, 0.f), fmaxf(a1h.y, 0.f));
                *(float4*)(smem + H0_OFF + wcol(r0))       = o0;
                *(float4*)(smem + H0_OFF + wcol(r0 + 128)) = o1;
            }
            __syncthreads();   // B2
        }

        // ================= h1 = relu(W1 @ h0) -> h1T =================
        {
            v2f a0l = {0.f, 0.f}, a0h = {0.f, 0.f};
            v2f a1l = {0.f, 0.f}, a1h = {0.f, 0.f};
            #pragma unroll 4
            for (int ci = 0; ci < 8; ++ci) {
                int c8 = kq * 8 + ci;
                uint4 u0 = w1p[c8 * 256 + r0];
                uint4 u1 = w1p[c8 * 256 + r0 + 128];
                #pragma unroll
                for (int m = 0; m < 8; ++m) {
                    float4 h = *(const float4*)(h0_base + ci * 128 + m * 16);
                    uint32_t q0 = u4get(u0, m >> 1), q1 = u4get(u1, m >> 1);
                    float f0 = (m & 1) ? bfhi(q0) : bflo(q0);
                    float f1 = (m & 1) ? bfhi(q1) : bflo(q1);
                    v2f s0 = {f0, f0}, s1 = {f1, f1};
                    v2f hl = {h.x, h.y}, hh = {h.z, h.w};
                    a0l = fma2(s0, hl, a0l); a0h = fma2(s0, hh, a0h);
                    a1l = fma2(s1, hl, a1l); a1h = fma2(s1, hh, a1h);
                }
            }
            a0l += shflx2(a0l, 16); a0h += shflx2(a0h, 16);
            a1l += shflx2(a1l, 16); a1h += shflx2(a1h, 16);
            a0l += shflx2(a0l, 32); a0h += shflx2(a0h, 32);
            a1l += shflx2(a1l, 32); a1h += shflx2(a1h, 32);
            if (kq == 0) {
                float4 o0 = make_float4(fmaxf(a0l.x, 0.f), fmaxf(a0l.y, 0.f),
                                        fmaxf(a0h.x, 0.f), fmaxf(a0h.y, 0.f));
                float4 o1 = make_float4(fmaxf(a1l.x, 0.f), fmaxf(a1l.y, 0.f),
                                        fmaxf(a1h.x, 0.f), fmaxf(a1h.y, 0.f));
                *(float4*)(smem + H1_OFF + wcol(r0))       = o0;
                *(float4*)(smem + H1_OFF + wcol(r0 + 128)) = o1;
            }
            __syncthreads();   // B3
        }

        // ================= x_new = V @ h1 ; update xbuf, xnext, (final) out =================
        {
            v2f al = {0.f, 0.f}, ah = {0.f, 0.f};
            #pragma unroll 4
            for (int ci = 0; ci < 8; ++ci) {
                int c8 = kq * 8 + ci;
                uint4 u = vp[c8 * 128 + r0];
                #pragma unroll
                for (int m = 0; m < 8; ++m) {
                    float4 h = *(const float4*)(h1_base + ci * 128 + m * 16);
                    uint32_t q = u4get(u, m >> 1);
                    float f = (m & 1) ? bfhi(q) : bflo(q);
                    v2f s = {f, f};
                    v2f hl = {h.x, h.y}, hh = {h.z, h.w};
                    al = fma2(s, hl, al); ah = fma2(s, hh, ah);
                }
            }
            al += shflx2(al, 16); ah += shflx2(ah, 16);
            al += shflx2(al, 32); ah += shflx2(ah, 32);
            if (kq == 0) {
                float4 a = make_float4(al.x, al.y, ah.x, ah.y);
                xbuf[0 * 128 + r0] = a.x;
                xbuf[1 * 128 + r0] = a.y;
                xbuf[2 * 128 + r0] = a.z;
                xbuf[3 * 128 + r0] = a.w;
                *(float4*)(smem + XNEXT_OFF + wcol(r0)) = a;   // x part of next hcat
                if (k == KSTEPS - 1) {
                    out[(size_t)(e0 + 0) * 128 + r0] = a.x;
                    out[(size_t)(e0 + 1) * 128 + r0] = a.y;
                    out[(size_t)(e0 + 2) * 128 + r0] = a.z;
                    out[(size_t)(e0 + 3) * 128 + r0] = a.w;
                }
            }
            __syncthreads();   // B4
        }
    }
}

extern "C" void kernel_launch(void* const* d_in, const int* in_sizes, int n_in,
                              void* d_out, int out_size, void* d_ws, size_t ws_size,
                              hipStream_t stream)
{
    const float* w  = (const float*)d_in[0];   // [4096,128,128]
    const float* b  = (const float*)d_in[1];   // [4096,128]
    const float* W0 = (const float*)d_in[2];   // [256,256]
    const float* W1 = (const float*)d_in[3];   // [256,256]
    const float* V  = (const float*)d_in[4];   // [128,256]
    float* out = (float*)d_out;                // [4096,128]
    uint16_t* wp = (uint16_t*)d_ws;            // 320 KB packed bf16 weights

    prep_kernel<<<640, 256, 0, stream>>>(W0, W1, V, wp);

    hipFuncSetAttribute((const void*)mlprnn_main,
                        hipFuncAttributeMaxDynamicSharedMemorySize, SMEM_BYTES);
    mlprnn_main<<<NBLOCKS, NTHREADS, SMEM_BYTES, stream>>>(w, b, wp, out);
}

// Round 6
// 459.329 us; speedup vs baseline: 1.9264x; 1.7778x over previous
//
#include <hip/hip_runtime.h>
#include <stdint.h>

#define KSTEPS 20
#define EPB 4          // batch elements per block
#define NBLOCKS 1024   // 4096 / EPB
#define NTHREADS 512

// ---- LDS layout (bytes) ----
// wq    : uint32 [4][128][64] bf16-pairs, pair-rotated swizzle = 131072 @0
// hcatB : bf16 [4][272]  (cols 0..127 = -grad, 128..255 = x)   =  2176 @131072
// h0B   : bf16 [4][272]                                        =  2176 @133248
// h1B   : bf16 [4][272]                                        =  2176 @135424
// xbuf  : f32  [4][132]  (f32 x for the grad matvec)           =  2112 @137600
#define WQ_OFF     0
#define HB_OFF     131072
#define H0B_OFF    133248
#define H1B_OFF    135424
#define XBUF_OFF   137600
#define SMEM_BYTES 139712

#define ACT_STRIDE 544   // bytes per batch row of bf16 activation buffers (272 u16)
#define XB_STRIDE  132   // floats per batch row of xbuf (128 + 4 pad)

typedef short bf16x8 __attribute__((ext_vector_type(8)));
typedef float f32x4  __attribute__((ext_vector_type(4)));

static __device__ __forceinline__ float bflo(uint32_t u) {
    union { uint32_t u; float f; } v; v.u = u << 16; return v.f;
}
static __device__ __forceinline__ float bfhi(uint32_t u) {
    union { uint32_t u; float f; } v; v.u = u & 0xffff0000u; return v.f;
}
static __device__ __forceinline__ uint32_t f2bf(float x) {  // RNE round to bf16 (as u16)
    union { float f; uint32_t u; } v; v.f = x;
    return (v.u + 0x7fffu + ((v.u >> 16) & 1u)) >> 16;
}
static __device__ __forceinline__ uint32_t packbf2(float a, float b) {
    return f2bf(a) | (f2bf(b) << 16);
}

// Pack shared MLP weights fp32 -> bf16 in layout [c][r][m] : Wp[(c*R + r)*8 + m] = W[r][8c+m]
// This is EXACTLY the mfma_f32_16x16x32_bf16 A-fragment layout: lane l of a wave
// covering M-tile mt loads uint4 (c*R + mt*16 + (l&15)) with c = kk*4 + (l>>4)
// -> 8 consecutive k for its row. One global load per fragment, zero duplication.
__global__ void prep_kernel(const float* __restrict__ W0, const float* __restrict__ W1,
                            const float* __restrict__ V, uint16_t* __restrict__ out)
{
    int i = blockIdx.x * 256 + threadIdx.x;   // 640 blocks * 256 = 163840
    float v;
    if (i < 65536) {
        int c = i >> 11, rest = i & 2047, r = rest >> 3, m = rest & 7;
        v = W0[r * 256 + c * 8 + m];
    } else if (i < 131072) {
        int j = i - 65536;
        int c = j >> 11, rest = j & 2047, r = rest >> 3, m = rest & 7;
        v = W1[r * 256 + c * 8 + m];
    } else {
        int j = i - 131072;
        int c = j >> 10, rest = j & 1023, r = rest >> 3, m = rest & 7;
        v = V[r * 256 + c * 8 + m];
    }
    out[i] = (uint16_t)f2bf(v);
}

// Round-5 post-mortem: conflicts fixed (128M->2M) but shuffle-reduce structure is
// a net loss vs R3 (816 vs 744): DS-pipe shuffles in a serial tail, splat movs,
// 3/4 idle lanes. Per-step budget 27K cy vs 2.8K cy of pure FMA issue -> 10x
// VALU overhead per MAC. The MLP phases are matmul-shaped (K=256) -> move them to
// MFMA (Guideline 10): 40 mfma_16x16x32_bf16 per wave per step replaces ~1500
// VALU ops. Batch=4 uses 4/16 N-cols (lanes col>=4 read col&3, outputs discarded)
// -> still ~4x the FP32 vector peak. Activations stored bf16 [batch][256]
// (+pad): B-frag = one ds_read_b128. C/D: col=lane&15, row=(lane>>4)*4+i (m89).
// grad matvec (9% of MACs, batch-distinct A) stays on the proven VALU path.
__global__
__attribute__((amdgpu_flat_work_group_size(512, 512), amdgpu_waves_per_eu(2, 2)))
void mlprnn_main(
    const float* __restrict__ w, const float* __restrict__ b,
    const uint16_t* __restrict__ wp, float* __restrict__ out)
{
    extern __shared__ char smem[];
    uint32_t* wq   = (uint32_t*)(smem + WQ_OFF);
    float*    xbuf = (float*)(smem + XBUF_OFF);

    const int t  = threadIdx.x;
    const int e0 = blockIdx.x * EPB;

    // ---- load this block's 4 w matrices -> LDS bf16, pair-rotated swizzle ----
    {
        const float4* wg = (const float4*)w;
        for (int it = 0; it < 32; ++it) {
            int g  = it * NTHREADS + t;       // 0..16383
            int e  = g >> 12;
            int gg = g & 4095;
            int r  = gg >> 5, q = gg & 31;
            float4 f = wg[(size_t)(e0 + e) * 4096 + gg];
            int s = (q + r) & 31;
            uint32_t* dst = wq + ((e * 128 + r) * 64 + 2 * s);
            dst[0] = packbf2(f.x, f.y);
            dst[1] = packbf2(f.z, f.w);
        }
    }
    // init x = 0 (f32 xbuf) and bf16 x-part of hcat = 0
    for (int i = t; i < 4 * XB_STRIDE; i += NTHREADS) xbuf[i] = 0.f;
    {
        int bi = t >> 7, r = t & 127;
        *(uint16_t*)(smem + HB_OFF + bi * ACT_STRIDE + 256 + 2 * r) = 0;
    }
    __syncthreads();

    // ---- matvec role: 2 waves per element, lane-per-row ----
    const int e_mv = t >> 7;                         // element 0..3
    const int r_mv = ((t >> 6) & 1) * 64 + (t & 63); // row 0..127
    const float breg = b[(size_t)(e0 + e_mv) * 128 + r_mv];
    const uint32_t* wrow = wq + ((e_mv * 128 + r_mv) * 64);
    const float4*   xv   = (const float4*)(xbuf + e_mv * XB_STRIDE);
    uint16_t* const grad_wr = (uint16_t*)(smem + HB_OFF + e_mv * ACT_STRIDE + 2 * r_mv);

    // ---- MFMA role ----
    const int l = t & 63, wv = t >> 6;               // wave 0..7
    const int row15 = l & 15;                        // A row within tile / C col (batch)
    const int kg    = l >> 4;                        // k-group / C row-group
    const int cm    = l & 3;                         // B source batch (dup for col>=4)
    const bool cok  = row15 < 4;                     // epilogue-active lanes
    const int mt0 = 2 * wv, mt1 = 2 * wv + 1;        // h0/h1 M-tiles; V tile = wv

    const bf16x8* w0v = (const bf16x8*)wp;           // [32][256]
    const bf16x8* w1v = w0v + 32 * 256;
    const bf16x8* vv  = w1v + 32 * 256;              // [32][128]

    const char* hbB = smem + HB_OFF  + cm * ACT_STRIDE + kg * 16;
    const char* h0B = smem + H0B_OFF + cm * ACT_STRIDE + kg * 16;
    const char* h1B = smem + H1B_OFF + cm * ACT_STRIDE + kg * 16;

    for (int k = 0; k < KSTEPS; ++k) {
        // ================= grad = w @ x - b ; hcatB[e][r] = bf16(-grad) =================
        {
            float acc = 0.f;
            #pragma unroll 8
            for (int j4 = 0; j4 < 32; ++j4) {
                int s = (j4 + r_mv) & 31;
                uint2 u = *(const uint2*)(wrow + 2 * s);
                float4 xq = xv[j4];
                acc += bflo(u.x) * xq.x + bfhi(u.x) * xq.y
                     + bflo(u.y) * xq.z + bfhi(u.y) * xq.w;
            }
            *grad_wr = (uint16_t)f2bf(breg - acc);   // -grad
        }
        __syncthreads();   // B1

        // ================= h0 = relu(W0 @ hcat)  [MFMA] =================
        {
            f32x4 acc0 = {0.f, 0.f, 0.f, 0.f};
            f32x4 acc1 = {0.f, 0.f, 0.f, 0.f};
            #pragma unroll 4
            for (int kk = 0; kk < 8; ++kk) {
                bf16x8 bf = *(const bf16x8*)(hbB + kk * 64);
                bf16x8 a0 = w0v[(kk * 4 + kg) * 256 + mt0 * 16 + row15];
                bf16x8 a1 = w0v[(kk * 4 + kg) * 256 + mt1 * 16 + row15];
                acc0 = __builtin_amdgcn_mfma_f32_16x16x32_bf16(a0, bf, acc0, 0, 0, 0);
                acc1 = __builtin_amdgcn_mfma_f32_16x16x32_bf16(a1, bf, acc1, 0, 0, 0);
            }
            if (cok) {
                uint2 q0 = { packbf2(fmaxf(acc0[0], 0.f), fmaxf(acc0[1], 0.f)),
                             packbf2(fmaxf(acc0[2], 0.f), fmaxf(acc0[3], 0.f)) };
                uint2 q1 = { packbf2(fmaxf(acc1[0], 0.f), fmaxf(acc1[1], 0.f)),
                             packbf2(fmaxf(acc1[2], 0.f), fmaxf(acc1[3], 0.f)) };
                *(uint2*)(smem + H0B_OFF + row15 * ACT_STRIDE + (mt0 * 16 + kg * 4) * 2) = q0;
                *(uint2*)(smem + H0B_OFF + row15 * ACT_STRIDE + (mt1 * 16 + kg * 4) * 2) = q1;
            }
            __syncthreads();   // B2
        }

        // ================= h1 = relu(W1 @ h0)  [MFMA] =================
        {
            f32x4 acc0 = {0.f, 0.f, 0.f, 0.f};
            f32x4 acc1 = {0.f, 0.f, 0.f, 0.f};
            #pragma unroll 4
            for (int kk = 0; kk < 8; ++kk) {
                bf16x8 bf = *(const bf16x8*)(h0B + kk * 64);
                bf16x8 a0 = w1v[(kk * 4 + kg) * 256 + mt0 * 16 + row15];
                bf16x8 a1 = w1v[(kk * 4 + kg) * 256 + mt1 * 16 + row15];
                acc0 = __builtin_amdgcn_mfma_f32_16x16x32_bf16(a0, bf, acc0, 0, 0, 0);
                acc1 = __builtin_amdgcn_mfma_f32_16x16x32_bf16(a1, bf, acc1, 0, 0, 0);
            }
            if (cok) {
                uint2 q0 = { packbf2(fmaxf(acc0[0], 0.f), fmaxf(acc0[1], 0.f)),
                             packbf2(fmaxf(acc0[2], 0.f), fmaxf(acc0[3], 0.f)) };
                uint2 q1 = { packbf2(fmaxf(acc1[0], 0.f), fmaxf(acc1[1], 0.f)),
                             packbf2(fmaxf(acc1[2], 0.f), fmaxf(acc1[3], 0.f)) };
                *(uint2*)(smem + H1B_OFF + row15 * ACT_STRIDE + (mt0 * 16 + kg * 4) * 2) = q0;
                *(uint2*)(smem + H1B_OFF + row15 * ACT_STRIDE + (mt1 * 16 + kg * 4) * 2) = q1;
            }
            __syncthreads();   // B3
        }

        // ================= x_new = V @ h1  [MFMA] ; update xbuf, hcat upper, out =================
        {
            f32x4 acc = {0.f, 0.f, 0.f, 0.f};
            #pragma unroll 4
            for (int kk = 0; kk < 8; ++kk) {
                bf16x8 bf = *(const bf16x8*)(h1B + kk * 64);
                bf16x8 av = vv[(kk * 4 + kg) * 128 + wv * 16 + row15];
                acc = __builtin_amdgcn_mfma_f32_16x16x32_bf16(av, bf, acc, 0, 0, 0);
            }
            if (cok) {
                const int r = wv * 16 + kg * 4;      // output rows r..r+3, batch row15
                *(f32x4*)(xbuf + row15 * XB_STRIDE + r) = acc;   // f32 x for matvec
                uint2 q = { packbf2(acc[0], acc[1]), packbf2(acc[2], acc[3]) };
                *(uint2*)(smem + HB_OFF + row15 * ACT_STRIDE + 256 + r * 2) = q;  // bf16 x
                if (k == KSTEPS - 1) {
                    *(f32x4*)(&out[(size_t)(e0 + row15) * 128 + r]) = acc;
                }
            }
            __syncthreads();   // B4
        }
    }
}

extern "C" void kernel_launch(void* const* d_in, const int* in_sizes, int n_in,
                              void* d_out, int out_size, void* d_ws, size_t ws_size,
                              hipStream_t stream)
{
    const float* w  = (const float*)d_in[0];   // [4096,128,128]
    const float* b  = (const float*)d_in[1];   // [4096,128]
    const float* W0 = (const float*)d_in[2];   // [256,256]
    const float* W1 = (const float*)d_in[3];   // [256,256]
    const float* V  = (const float*)d_in[4];   // [128,256]
    float* out = (float*)d_out;                // [4096,128]
    uint16_t* wp = (uint16_t*)d_ws;            // 320 KB packed bf16 weights

    prep_kernel<<<640, 256, 0, stream>>>(W0, W1, V, wp);

    hipFuncSetAttribute((const void*)mlprnn_main,
                        hipFuncAttributeMaxDynamicSharedMemorySize, SMEM_BYTES);
    mlprnn_main<<<NBLOCKS, NTHREADS, SMEM_BYTES, stream>>>(w, b, wp, out);
}

// Round 7
// 300.587 us; speedup vs baseline: 2.9438x; 1.5281x over previous
//
#include <hip/hip_runtime.h>
#include <stdint.h>

#define KSTEPS 20
#define EPB 4          // batch elements per block
#define NBLOCKS 1024   // 4096 / EPB
#define NTHREADS 512

// ---- LDS layout (bytes) ----
// wq    : uint32 [4][128][64] bf16-pairs, pair-rotated swizzle = 131072 @0
// hcatB : bf16 [4][272]  (cols 0..127 = -grad, 128..255 = x)   =  2176 @131072
// h0B   : bf16 [4][272]                                        =  2176 @133248
// h1B   : bf16 [4][272]                                        =  2176 @135424
// xbuf  : f32  [4][132]  (f32 x for the grad matvec)           =  2112 @137600
#define WQ_OFF     0
#define HB_OFF     131072
#define H0B_OFF    133248
#define H1B_OFF    135424
#define XBUF_OFF   137600
#define SMEM_BYTES 139712

#define ACT_STRIDE 544   // bytes per batch row of bf16 activation buffers (272 u16)
#define XB_STRIDE  132   // floats per batch row of xbuf (128 + 4 pad)

typedef short bf16x8 __attribute__((ext_vector_type(8)));
typedef float f32x4  __attribute__((ext_vector_type(4)));

static __device__ __forceinline__ float bflo(uint32_t u) {
    union { uint32_t u; float f; } v; v.u = u << 16; return v.f;
}
static __device__ __forceinline__ float bfhi(uint32_t u) {
    union { uint32_t u; float f; } v; v.u = u & 0xffff0000u; return v.f;
}
static __device__ __forceinline__ uint32_t f2bf(float x) {  // RNE round to bf16 (as u16)
    union { float f; uint32_t u; } v; v.f = x;
    return (v.u + 0x7fffu + ((v.u >> 16) & 1u)) >> 16;
}
static __device__ __forceinline__ uint32_t packbf2(float a, float b) {
    return f2bf(a) | (f2bf(b) << 16);
}

// Pack shared MLP weights fp32 -> bf16 in layout [c][r][m] : Wp[(c*R + r)*8 + m] = W[r][8c+m]
// This is EXACTLY the mfma_f32_16x16x32_bf16 A-fragment layout: lane l of a wave
// covering M-tile mt loads uint4 (c*R + mt*16 + (l&15)) with c = kk*4 + (l>>4)
// -> 8 consecutive k for its row. One global load per fragment, zero duplication.
__global__ void prep_kernel(const float* __restrict__ W0, const float* __restrict__ W1,
                            const float* __restrict__ V, uint16_t* __restrict__ out)
{
    int i = blockIdx.x * 256 + threadIdx.x;   // 640 blocks * 256 = 163840
    float v;
    if (i < 65536) {
        int c = i >> 11, rest = i & 2047, r = rest >> 3, m = rest & 7;
        v = W0[r * 256 + c * 8 + m];
    } else if (i < 131072) {
        int j = i - 65536;
        int c = j >> 11, rest = j & 2047, r = rest >> 3, m = rest & 7;
        v = W1[r * 256 + c * 8 + m];
    } else {
        int j = i - 131072;
        int c = j >> 10, rest = j & 1023, r = rest >> 3, m = rest & 7;
        v = V[r * 256 + c * 8 + m];
    }
    out[i] = (uint16_t)f2bf(v);
}

// Round-6 post-mortem: MFMA engaged (8.3% util, 459us) but each step re-fetches
// the full 320KB weight image from L2 per CU (10MB/XCD/step; at 1800 B/cy that's
// ~5.8K of the observed ~10K cy/step, serialized into phase bursts by barriers).
// Fix: weights are loop-invariant -> hoist all 40 A-fragments (640B/lane = 160
// VGPRs) into registers, issued BEFORE w-staging so L2 latency hides under HBM
// staging. Base demand was 88 VGPR -> 88+160 ~ 240 fits the 256-reg cap at the
// LDS-forced 2 waves/EU (unlike R2, where base demand made this spill).
// All kk loops fully unrolled so fragment indices are compile-time (rule #20).
__global__
__attribute__((amdgpu_flat_work_group_size(512, 512), amdgpu_waves_per_eu(2, 2)))
void mlprnn_main(
    const float* __restrict__ w, const float* __restrict__ b,
    const uint16_t* __restrict__ wp, float* __restrict__ out)
{
    extern __shared__ char smem[];
    uint32_t* wq   = (uint32_t*)(smem + WQ_OFF);
    float*    xbuf = (float*)(smem + XBUF_OFF);

    const int t  = threadIdx.x;
    const int e0 = blockIdx.x * EPB;

    // ---- MFMA role ----
    const int l = t & 63, wv = t >> 6;               // wave 0..7
    const int row15 = l & 15;                        // A row within tile / C col (batch)
    const int kg    = l >> 4;                        // k-group / C row-group
    const int cm    = l & 3;                         // B source batch (dup for col>=4)
    const bool cok  = row15 < 4;                     // epilogue-active lanes
    const int mt0 = 2 * wv, mt1 = 2 * wv + 1;        // h0/h1 M-tiles; V tile = wv

    const bf16x8* w0v = (const bf16x8*)wp;           // [32][256]
    const bf16x8* w1v = w0v + 32 * 256;
    const bf16x8* vv  = w1v + 32 * 256;              // [32][128]

    // ---- hoist all loop-invariant A-fragments into registers (160 VGPRs) ----
    // issued first: their L2 latency hides under the HBM w-staging below.
    bf16x8 a0w[8], a1w[8], b0w[8], b1w[8], vw[8];
    #pragma unroll
    for (int kk = 0; kk < 8; ++kk) {
        a0w[kk] = w0v[(kk * 4 + kg) * 256 + mt0 * 16 + row15];
        a1w[kk] = w0v[(kk * 4 + kg) * 256 + mt1 * 16 + row15];
        b0w[kk] = w1v[(kk * 4 + kg) * 256 + mt0 * 16 + row15];
        b1w[kk] = w1v[(kk * 4 + kg) * 256 + mt1 * 16 + row15];
        vw[kk]  = vv[(kk * 4 + kg) * 128 + wv * 16 + row15];
    }

    // ---- load this block's 4 w matrices -> LDS bf16, pair-rotated swizzle ----
    {
        const float4* wg = (const float4*)w;
        for (int it = 0; it < 32; ++it) {
            int g  = it * NTHREADS + t;       // 0..16383
            int e  = g >> 12;
            int gg = g & 4095;
            int r  = gg >> 5, q = gg & 31;
            float4 f = wg[(size_t)(e0 + e) * 4096 + gg];
            int s = (q + r) & 31;
            uint32_t* dst = wq + ((e * 128 + r) * 64 + 2 * s);
            dst[0] = packbf2(f.x, f.y);
            dst[1] = packbf2(f.z, f.w);
        }
    }
    // init x = 0 (f32 xbuf) and bf16 x-part of hcat = 0
    for (int i = t; i < 4 * XB_STRIDE; i += NTHREADS) xbuf[i] = 0.f;
    {
        int bi = t >> 7, r = t & 127;
        *(uint16_t*)(smem + HB_OFF + bi * ACT_STRIDE + 256 + 2 * r) = 0;
    }
    __syncthreads();

    // ---- matvec role: 2 waves per element, lane-per-row ----
    const int e_mv = t >> 7;                         // element 0..3
    const int r_mv = ((t >> 6) & 1) * 64 + (t & 63); // row 0..127
    const float breg = b[(size_t)(e0 + e_mv) * 128 + r_mv];
    const uint32_t* wrow = wq + ((e_mv * 128 + r_mv) * 64);
    const float4*   xv   = (const float4*)(xbuf + e_mv * XB_STRIDE);
    uint16_t* const grad_wr = (uint16_t*)(smem + HB_OFF + e_mv * ACT_STRIDE + 2 * r_mv);

    const char* hbB = smem + HB_OFF  + cm * ACT_STRIDE + kg * 16;
    const char* h0B = smem + H0B_OFF + cm * ACT_STRIDE + kg * 16;
    const char* h1B = smem + H1B_OFF + cm * ACT_STRIDE + kg * 16;

    for (int k = 0; k < KSTEPS; ++k) {
        // ================= grad = w @ x - b ; hcatB[e][r] = bf16(-grad) =================
        {
            float acc = 0.f;
            #pragma unroll 8
            for (int j4 = 0; j4 < 32; ++j4) {
                int s = (j4 + r_mv) & 31;
                uint2 u = *(const uint2*)(wrow + 2 * s);
                float4 xq = xv[j4];
                acc += bflo(u.x) * xq.x + bfhi(u.x) * xq.y
                     + bflo(u.y) * xq.z + bfhi(u.y) * xq.w;
            }
            *grad_wr = (uint16_t)f2bf(breg - acc);   // -grad
        }
        __syncthreads();   // B1

        // ================= h0 = relu(W0 @ hcat)  [MFMA] =================
        {
            f32x4 acc0 = {0.f, 0.f, 0.f, 0.f};
            f32x4 acc1 = {0.f, 0.f, 0.f, 0.f};
            #pragma unroll
            for (int kk = 0; kk < 8; ++kk) {
                bf16x8 bf = *(const bf16x8*)(hbB + kk * 64);
                acc0 = __builtin_amdgcn_mfma_f32_16x16x32_bf16(a0w[kk], bf, acc0, 0, 0, 0);
                acc1 = __builtin_amdgcn_mfma_f32_16x16x32_bf16(a1w[kk], bf, acc1, 0, 0, 0);
            }
            if (cok) {
                uint2 q0 = { packbf2(fmaxf(acc0[0], 0.f), fmaxf(acc0[1], 0.f)),
                             packbf2(fmaxf(acc0[2], 0.f), fmaxf(acc0[3], 0.f)) };
                uint2 q1 = { packbf2(fmaxf(acc1[0], 0.f), fmaxf(acc1[1], 0.f)),
                             packbf2(fmaxf(acc1[2], 0.f), fmaxf(acc1[3], 0.f)) };
                *(uint2*)(smem + H0B_OFF + row15 * ACT_STRIDE + (mt0 * 16 + kg * 4) * 2) = q0;
                *(uint2*)(smem + H0B_OFF + row15 * ACT_STRIDE + (mt1 * 16 + kg * 4) * 2) = q1;
            }
            __syncthreads();   // B2
        }

        // ================= h1 = relu(W1 @ h0)  [MFMA] =================
        {
            f32x4 acc0 = {0.f, 0.f, 0.f, 0.f};
            f32x4 acc1 = {0.f, 0.f, 0.f, 0.f};
            #pragma unroll
            for (int kk = 0; kk < 8; ++kk) {
                bf16x8 bf = *(const bf16x8*)(h0B + kk * 64);
                acc0 = __builtin_amdgcn_mfma_f32_16x16x32_bf16(b0w[kk], bf, acc0, 0, 0, 0);
                acc1 = __builtin_amdgcn_mfma_f32_16x16x32_bf16(b1w[kk], bf, acc1, 0, 0, 0);
            }
            if (cok) {
                uint2 q0 = { packbf2(fmaxf(acc0[0], 0.f), fmaxf(acc0[1], 0.f)),
                             packbf2(fmaxf(acc0[2], 0.f), fmaxf(acc0[3], 0.f)) };
                uint2 q1 = { packbf2(fmaxf(acc1[0], 0.f), fmaxf(acc1[1], 0.f)),
                             packbf2(fmaxf(acc1[2], 0.f), fmaxf(acc1[3], 0.f)) };
                *(uint2*)(smem + H1B_OFF + row15 * ACT_STRIDE + (mt0 * 16 + kg * 4) * 2) = q0;
                *(uint2*)(smem + H1B_OFF + row15 * ACT_STRIDE + (mt1 * 16 + kg * 4) * 2) = q1;
            }
            __syncthreads();   // B3
        }

        // ================= x_new = V @ h1  [MFMA] ; update xbuf, hcat upper, out =================
        {
            f32x4 acc = {0.f, 0.f, 0.f, 0.f};
            #pragma unroll
            for (int kk = 0; kk < 8; ++kk) {
                bf16x8 bf = *(const bf16x8*)(h1B + kk * 64);
                acc = __builtin_amdgcn_mfma_f32_16x16x32_bf16(vw[kk], bf, acc, 0, 0, 0);
            }
            if (cok) {
                const int r = wv * 16 + kg * 4;      // output rows r..r+3, batch row15
                *(f32x4*)(xbuf + row15 * XB_STRIDE + r) = acc;   // f32 x for matvec
                uint2 q = { packbf2(acc[0], acc[1]), packbf2(acc[2], acc[3]) };
                *(uint2*)(smem + HB_OFF + row15 * ACT_STRIDE + 256 + r * 2) = q;  // bf16 x
                if (k == KSTEPS - 1) {
                    *(f32x4*)(&out[(size_t)(e0 + row15) * 128 + r]) = acc;
                }
            }
            __syncthreads();   // B4
        }
    }
}

extern "C" void kernel_launch(void* const* d_in, const int* in_sizes, int n_in,
                              void* d_out, int out_size, void* d_ws, size_t ws_size,
                              hipStream_t stream)
{
    const float* w  = (const float*)d_in[0];   // [4096,128,128]
    const float* b  = (const float*)d_in[1];   // [4096,128]
    const float* W0 = (const float*)d_in[2];   // [256,256]
    const float* W1 = (const float*)d_in[3];   // [256,256]
    const float* V  = (const float*)d_in[4];   // [128,256]
    float* out = (float*)d_out;                // [4096,128]
    uint16_t* wp = (uint16_t*)d_ws;            // 320 KB packed bf16 weights

    prep_kernel<<<640, 256, 0, stream>>>(W0, W1, V, wp);

    hipFuncSetAttribute((const void*)mlprnn_main,
                        hipFuncAttributeMaxDynamicSharedMemorySize, SMEM_BYTES);
    mlprnn_main<<<NBLOCKS, NTHREADS, SMEM_BYTES, stream>>>(w, b, wp, out);
}

// Round 8
// 218.332 us; speedup vs baseline: 4.0528x; 1.3767x over previous
//
#include <hip/hip_runtime.h>
#include <stdint.h>

#define KSTEPS 20
#define EPB 4          // batch elements per block
#define NBLOCKS 1024   // 4096 / EPB
#define NTHREADS 512

// ---- LDS layout (bytes) ----
// wq    : bf16 [4][128 rows][128 k], NEGATED, XOR-swizzled       = 131072 @0
//         byte(e,row,k) = e*32768 + row*256 + k*2, ^((row&7)<<4)
// hcatB : bf16 [4][272]  (cols 0..127 = -grad, 128..255 = x)    =  2176 @131072
// h0B   : bf16 [4][272]                                          =  2176 @133248
// h1B   : bf16 [4][272]                                          =  2176 @135424
#define WQ_OFF     0
#define HB_OFF     131072
#define H0B_OFF    133248
#define H1B_OFF    135424
#define SMEM_BYTES 137600

#define ACT_STRIDE 544   // bytes per batch row of bf16 activation buffers (272 u16)

typedef short bf16x8 __attribute__((ext_vector_type(8)));
typedef float f32x4  __attribute__((ext_vector_type(4)));

static __device__ __forceinline__ uint32_t f2bf(float x) {  // RNE round to bf16 (as u16)
    union { float f; uint32_t u; } v; v.f = x;
    return (v.u + 0x7fffu + ((v.u >> 16) & 1u)) >> 16;
}
static __device__ __forceinline__ uint32_t packbf2(float a, float b) {
    return f2bf(a) | (f2bf(b) << 16);
}

// Pack shared MLP weights fp32 -> bf16 in layout [c][r][m] : Wp[(c*R + r)*8 + m] = W[r][8c+m]
// == the mfma_f32_16x16x32_bf16 A-fragment layout (lane = row l&15, k-group l>>4).
__global__ void prep_kernel(const float* __restrict__ W0, const float* __restrict__ W1,
                            const float* __restrict__ V, uint16_t* __restrict__ out)
{
    int i = blockIdx.x * 256 + threadIdx.x;   // 640 blocks * 256 = 163840
    float v;
    if (i < 65536) {
        int c = i >> 11, rest = i & 2047, r = rest >> 3, m = rest & 7;
        v = W0[r * 256 + c * 8 + m];
    } else if (i < 131072) {
        int j = i - 65536;
        int c = j >> 11, rest = j & 2047, r = rest >> 3, m = rest & 7;
        v = W1[r * 256 + c * 8 + m];
    } else {
        int j = i - 131072;
        int c = j >> 10, rest = j & 1023, r = rest >> 3, m = rest & 7;
        v = V[r * 256 + c * 8 + m];
    }
    out[i] = (uint16_t)f2bf(v);
}

// Round-7 post-mortem: weight hoist worked (300us, no spills). The grad matvec is
// now the dominant phase (~1.5-2.5K cy/wave on VALU vs ~400 cy for each MFMA
// phase; VALUBusy 49% vs MfmaUtil 12%). It is matmul-shaped (K=128) -> move it to
// MFMA too: w stored NEGATED bf16 [e][row][k] in LDS with (row&7)<<4 XOR swizzle
// (A-fragment ds_read_b128 hits the 8-cy floor), all 16 B-cols fed the same x
// (broadcast reads; every D column = the same matvec), acc seeded with hoisted b
// regs so acc = b + (-w)@x = -grad directly. f32 xbuf eliminated (x consumed as
// bf16 from hcatB). Epilogue: 4 exec-masked tile writes, static indices (#20).
__global__
__attribute__((amdgpu_flat_work_group_size(512, 512), amdgpu_waves_per_eu(2, 2)))
void mlprnn_main(
    const float* __restrict__ w, const float* __restrict__ b,
    const uint16_t* __restrict__ wp, float* __restrict__ out)
{
    extern __shared__ char smem[];

    const int t  = threadIdx.x;
    const int e0 = blockIdx.x * EPB;

    // ---- MFMA lane roles ----
    const int l = t & 63, wv = t >> 6;               // wave 0..7
    const int row15 = l & 15;                        // A row within tile / C col
    const int kg    = l >> 4;                        // k-group / C row-group
    const int cm    = l & 3;                         // MLP B source batch
    const bool cok  = row15 < 4;                     // MLP epilogue lanes
    const int mt0 = 2 * wv, mt1 = 2 * wv + 1;        // h0/h1 M-tiles; V tile = wv

    // ---- grad-phase roles: wave -> (element, M-half) ----
    const int e_g  = wv >> 1;                        // element 0..3
    const int mh   = wv & 1;                         // M-half (64 rows)

    const bf16x8* w0v = (const bf16x8*)wp;           // [32][256]
    const bf16x8* w1v = w0v + 32 * 256;
    const bf16x8* vv  = w1v + 32 * 256;              // [32][128]

    // ---- hoist loop-invariant MLP A-fragments into registers (160 VGPRs) ----
    bf16x8 a0w[8], a1w[8], b0w[8], b1w[8], vw[8];
    #pragma unroll
    for (int kk = 0; kk < 8; ++kk) {
        a0w[kk] = w0v[(kk * 4 + kg) * 256 + mt0 * 16 + row15];
        a1w[kk] = w0v[(kk * 4 + kg) * 256 + mt1 * 16 + row15];
        b0w[kk] = w1v[(kk * 4 + kg) * 256 + mt0 * 16 + row15];
        b1w[kk] = w1v[(kk * 4 + kg) * 256 + mt1 * 16 + row15];
        vw[kk]  = vv[(kk * 4 + kg) * 128 + wv * 16 + row15];
    }
    // ---- hoist b for the grad phase: acc seed = b rows (mh*64 + mt*16 + kg*4 ..+4)
    f32x4 bseed[4];
    #pragma unroll
    for (int mt = 0; mt < 4; ++mt)
        bseed[mt] = *(const f32x4*)(b + (size_t)(e0 + e_g) * 128 + mh * 64 + mt * 16 + kg * 4);

    // ---- stage this block's 4 w matrices -> LDS, NEGATED bf16, XOR swizzle ----
    {
        const float4* wg = (const float4*)w;
        for (int it = 0; it < 32; ++it) {
            int g  = it * NTHREADS + t;       // 0..16383
            int e  = g >> 12;
            int gg = g & 4095;
            int r  = gg >> 5, q = gg & 31;    // row r, k-quad q (k0 = 4q)
            float4 f = wg[(size_t)(e0 + e) * 4096 + gg];
            uint2 pk = { packbf2(-f.x, -f.y), packbf2(-f.z, -f.w) };
            int byte = e * 32768 + r * 256 + q * 8;
            byte ^= (r & 7) << 4;
            *(uint2*)(smem + WQ_OFF + byte) = pk;
        }
    }
    // init bf16 x-part of hcat = 0
    {
        int bi = t >> 7, r = t & 127;
        *(uint16_t*)(smem + HB_OFF + bi * ACT_STRIDE + 256 + 2 * r) = 0;
    }
    __syncthreads();

    // grad-phase LDS bases
    const char* wqA = smem + WQ_OFF + e_g * 32768 + (mh * 64 + row15) * 256;
    const int   wqx = (row15 & 7) << 4;              // XOR term (row&7 == row15&7)
    const char* xB  = smem + HB_OFF + e_g * ACT_STRIDE + 256 + kg * 16;

    // MLP-phase LDS bases
    const char* hbB = smem + HB_OFF  + cm * ACT_STRIDE + kg * 16;
    const char* h0B = smem + H0B_OFF + cm * ACT_STRIDE + kg * 16;
    const char* h1B = smem + H1B_OFF + cm * ACT_STRIDE + kg * 16;

    for (int k = 0; k < KSTEPS; ++k) {
        // ========== -grad = b + (-w) @ x   [MFMA, all 16 cols identical] ==========
        {
            // B fragments: x[kt*32 + kg*8 .. +8] bf16, broadcast within kg group
            bf16x8 bx[4];
            #pragma unroll
            for (int kt = 0; kt < 4; ++kt)
                bx[kt] = *(const bf16x8*)(xB + kt * 64);

            f32x4 ag0 = bseed[0], ag1 = bseed[1], ag2 = bseed[2], ag3 = bseed[3];
            #pragma unroll
            for (int kt = 0; kt < 4; ++kt) {
                bf16x8 a0 = *(const bf16x8*)(wqA + ((0 * 16) * 256 + kt * 64 + kg * 16 ^ wqx));
                bf16x8 a1 = *(const bf16x8*)(wqA + ((1 * 16) * 256 + kt * 64 + kg * 16 ^ wqx));
                bf16x8 a2 = *(const bf16x8*)(wqA + ((2 * 16) * 256 + kt * 64 + kg * 16 ^ wqx));
                bf16x8 a3 = *(const bf16x8*)(wqA + ((3 * 16) * 256 + kt * 64 + kg * 16 ^ wqx));
                ag0 = __builtin_amdgcn_mfma_f32_16x16x32_bf16(a0, bx[kt], ag0, 0, 0, 0);
                ag1 = __builtin_amdgcn_mfma_f32_16x16x32_bf16(a1, bx[kt], ag1, 0, 0, 0);
                ag2 = __builtin_amdgcn_mfma_f32_16x16x32_bf16(a2, bx[kt], ag2, 0, 0, 0);
                ag3 = __builtin_amdgcn_mfma_f32_16x16x32_bf16(a3, bx[kt], ag3, 0, 0, 0);
            }
            // epilogue: lane col row15==mt writes tile mt's rows kg*4..+4 (static idx)
            char* gw = smem + HB_OFF + e_g * ACT_STRIDE;
            if (row15 == 0) *(uint2*)(gw + (mh * 64 + 0 * 16 + kg * 4) * 2)
                = (uint2){ packbf2(ag0[0], ag0[1]), packbf2(ag0[2], ag0[3]) };
            if (row15 == 1) *(uint2*)(gw + (mh * 64 + 1 * 16 + kg * 4) * 2)
                = (uint2){ packbf2(ag1[0], ag1[1]), packbf2(ag1[2], ag1[3]) };
            if (row15 == 2) *(uint2*)(gw + (mh * 64 + 2 * 16 + kg * 4) * 2)
                = (uint2){ packbf2(ag2[0], ag2[1]), packbf2(ag2[2], ag2[3]) };
            if (row15 == 3) *(uint2*)(gw + (mh * 64 + 3 * 16 + kg * 4) * 2)
                = (uint2){ packbf2(ag3[0], ag3[1]), packbf2(ag3[2], ag3[3]) };
        }
        __syncthreads();   // B1

        // ================= h0 = relu(W0 @ hcat)  [MFMA] =================
        {
            f32x4 acc0 = {0.f, 0.f, 0.f, 0.f};
            f32x4 acc1 = {0.f, 0.f, 0.f, 0.f};
            #pragma unroll
            for (int kk = 0; kk < 8; ++kk) {
                bf16x8 bf = *(const bf16x8*)(hbB + kk * 64);
                acc0 = __builtin_amdgcn_mfma_f32_16x16x32_bf16(a0w[kk], bf, acc0, 0, 0, 0);
                acc1 = __builtin_amdgcn_mfma_f32_16x16x32_bf16(a1w[kk], bf, acc1, 0, 0, 0);
            }
            if (cok) {
                uint2 q0 = { packbf2(fmaxf(acc0[0], 0.f), fmaxf(acc0[1], 0.f)),
                             packbf2(fmaxf(acc0[2], 0.f), fmaxf(acc0[3], 0.f)) };
                uint2 q1 = { packbf2(fmaxf(acc1[0], 0.f), fmaxf(acc1[1], 0.f)),
                             packbf2(fmaxf(acc1[2], 0.f), fmaxf(acc1[3], 0.f)) };
                *(uint2*)(smem + H0B_OFF + row15 * ACT_STRIDE + (mt0 * 16 + kg * 4) * 2) = q0;
                *(uint2*)(smem + H0B_OFF + row15 * ACT_STRIDE + (mt1 * 16 + kg * 4) * 2) = q1;
            }
            __syncthreads();   // B2
        }

        // ================= h1 = relu(W1 @ h0)  [MFMA] =================
        {
            f32x4 acc0 = {0.f, 0.f, 0.f, 0.f};
            f32x4 acc1 = {0.f, 0.f, 0.f, 0.f};
            #pragma unroll
            for (int kk = 0; kk < 8; ++kk) {
                bf16x8 bf = *(const bf16x8*)(h0B + kk * 64);
                acc0 = __builtin_amdgcn_mfma_f32_16x16x32_bf16(b0w[kk], bf, acc0, 0, 0, 0);
                acc1 = __builtin_amdgcn_mfma_f32_16x16x32_bf16(b1w[kk], bf, acc1, 0, 0, 0);
            }
            if (cok) {
                uint2 q0 = { packbf2(fmaxf(acc0[0], 0.f), fmaxf(acc0[1], 0.f)),
                             packbf2(fmaxf(acc0[2], 0.f), fmaxf(acc0[3], 0.f)) };
                uint2 q1 = { packbf2(fmaxf(acc1[0], 0.f), fmaxf(acc1[1], 0.f)),
                             packbf2(fmaxf(acc1[2], 0.f), fmaxf(acc1[3], 0.f)) };
                *(uint2*)(smem + H1B_OFF + row15 * ACT_STRIDE + (mt0 * 16 + kg * 4) * 2) = q0;
                *(uint2*)(smem + H1B_OFF + row15 * ACT_STRIDE + (mt1 * 16 + kg * 4) * 2) = q1;
            }
            __syncthreads();   // B3
        }

        // ========== x_new = V @ h1  [MFMA] ; update hcat x-part, (final) out ==========
        {
            f32x4 acc = {0.f, 0.f, 0.f, 0.f};
            #pragma unroll
            for (int kk = 0; kk < 8; ++kk) {
                bf16x8 bf = *(const bf16x8*)(h1B + kk * 64);
                acc = __builtin_amdgcn_mfma_f32_16x16x32_bf16(vw[kk], bf, acc, 0, 0, 0);
            }
            if (cok) {
                const int r = wv * 16 + kg * 4;      // output rows r..r+3, batch row15
                uint2 q = { packbf2(acc[0], acc[1]), packbf2(acc[2], acc[3]) };
                *(uint2*)(smem + HB_OFF + row15 * ACT_STRIDE + 256 + r * 2) = q;  // bf16 x
                if (k == KSTEPS - 1) {
                    *(f32x4*)(&out[(size_t)(e0 + row15) * 128 + r]) = acc;
                }
            }
            __syncthreads();   // B4
        }
    }
}

extern "C" void kernel_launch(void* const* d_in, const int* in_sizes, int n_in,
                              void* d_out, int out_size, void* d_ws, size_t ws_size,
                              hipStream_t stream)
{
    const float* w  = (const float*)d_in[0];   // [4096,128,128]
    const float* b  = (const float*)d_in[1];   // [4096,128]
    const float* W0 = (const float*)d_in[2];   // [256,256]
    const float* W1 = (const float*)d_in[3];   // [256,256]
    const float* V  = (const float*)d_in[4];   // [128,256]
    float* out = (float*)d_out;                // [4096,128]
    uint16_t* wp = (uint16_t*)d_ws;            // 320 KB packed bf16 weights

    prep_kernel<<<640, 256, 0, stream>>>(W0, W1, V, wp);

    hipFuncSetAttribute((const void*)mlprnn_main,
                        hipFuncAttributeMaxDynamicSharedMemorySize, SMEM_BYTES);
    mlprnn_main<<<NBLOCKS, NTHREADS, SMEM_BYTES, stream>>>(w, b, wp, out);
}